// Round 2
// 184.208 us; speedup vs baseline: 1.2255x; 1.2255x over previous
//
#include <hip/hip_runtime.h>

// SSIM, fused separable-conv single pass + reduce.
// x,y: [16,3,512,512] f32; window: [3,1,11,11] f32 (separable Gaussian).
// Output: scalar mean SSIM (f32).
//
// V2b: NO LDS staging of x/y. Phase V reads x,y directly from global
// (per-block working set 26x78x2x4B = 16 KB -> L1/L2 cached; lane-consecutive
// coalesced b32 loads). LDS now holds only vv (24.3 KB) -> 6 blocks/CU
// (was 4 at 40.6 KB), and the staging loop's VALU + LDS writes + one
// barrier are gone. Edge blocks (30%) take a block-uniform clamped path.
// Fix vs V2: readfirstlane must be bit-cast (int builtin), not value-cast.
//
// Phase-H LDS reads stay vectorized ds_read_b128: vv is column-shifted by 2
// (vv[c] = vconv at staged col c+2) so each output-quad's 14-tap window
// [j0+1 .. j0+14] sits inside the aligned 16-float span [j0 .. j0+16).

#define IMG_H 512
#define IMG_W 512
#define NC    48            // 16 batches * 3 channels

constexpr int TW = 64;      // output tile width
constexpr int TH = 16;      // output tile height
constexpr int VW = 76;      // vv stride (multiple of 4 for b128 alignment)
constexpr int NBLK = (IMG_W / TW) * (IMG_H / TH) * NC;   // 12288

__global__ __launch_bounds__(256, 6)
void ssim_fused(const float* __restrict__ x, const float* __restrict__ y,
                const float* __restrict__ w, double* __restrict__ part,
                int use_atomic)
{
    __shared__ __align__(16) float vv[5][TH][VW];  // vmu1, vmu2, vxx, vyy, vxy
    __shared__ float wsum[4];

    const int tid = threadIdx.x;
    const int x0 = blockIdx.x * TW - 8;    // virtual staged col 0
    const int y0 = blockIdx.y * TH - 5;    // virtual staged row 0
    const float* __restrict__ xp = x + (size_t)blockIdx.z * (IMG_H * IMG_W);
    const float* __restrict__ yp = y + (size_t)blockIdx.z * (IMG_H * IMG_W);

    // 1D gaussian from window row 5: w2d[5][k] = g5*g[k], g[k] = w[55+k]/sqrt(w[60]).
    // Uniform across lanes -> hoist to SGPRs via readfirstlane (BIT-cast: the
    // builtin is int->int; a value cast truncates floats to 0).
    float g[11];
    {
        const float g5inv = 1.0f / sqrtf(w[55 + 5]);
        #pragma unroll
        for (int k = 0; k < 11; ++k)
            g[k] = __uint_as_float(
                (unsigned)__builtin_amdgcn_readfirstlane(
                    (int)__float_as_uint(w[55 + k] * g5inv)));
    }

    // Accessed region: rows y0 .. y0+25, cols x0+2 .. x0+76.
    const bool interior = (y0 >= 0) & (y0 + 25 < IMG_H)
                        & (x0 + 2 >= 0) & (x0 + 76 < IMG_W);

    // ---- Phase V: vertical 11-tap conv of {x,y,xx,yy,xy} at image col
    //      x0+c+2, 4-row register blocking, inputs straight from global.
    //      vv cols 0..74 written (col 75 left unwritten, never consumed).
    for (int t = tid; t < 75 * 4; t += 256) {
        const int c   = t % 75;
        const int r0  = (t / 75) << 2;
        const int gc  = x0 + c + 2;
        const int gr0 = y0 + r0;
        float xv[14], yv[14], xxv[14], yyv[14], xyv[14];
        if (interior) {
            const unsigned base = (unsigned)(gr0 * IMG_W + gc);
            #pragma unroll
            for (int k = 0; k < 14; ++k) {
                const float a = xp[base + (unsigned)(k * IMG_W)];
                const float b = yp[base + (unsigned)(k * IMG_W)];
                xv[k] = a; yv[k] = b;
                xxv[k] = a * a; yyv[k] = b * b; xyv[k] = a * b;
            }
        } else {
            const int  cc  = min(max(gc, 0), IMG_W - 1);
            const bool okc = ((unsigned)gc < (unsigned)IMG_W);
            #pragma unroll
            for (int k = 0; k < 14; ++k) {
                const int  gr = gr0 + k;
                const int  cr = min(max(gr, 0), IMG_H - 1);
                const bool ok = okc & ((unsigned)gr < (unsigned)IMG_H);
                const unsigned idx = (unsigned)(cr * IMG_W + cc);
                const float a = ok ? xp[idx] : 0.0f;   // zero padding
                const float b = ok ? yp[idx] : 0.0f;
                xv[k] = a; yv[k] = b;
                xxv[k] = a * a; yyv[k] = b * b; xyv[k] = a * b;
            }
        }
        #pragma unroll
        for (int j = 0; j < 4; ++j) {
            float s0 = 0.f, s1 = 0.f, s2 = 0.f, s3 = 0.f, s4 = 0.f;
            #pragma unroll
            for (int k = 0; k < 11; ++k) {
                const float gk = g[k];
                s0 = fmaf(gk, xv[j + k],  s0);
                s1 = fmaf(gk, yv[j + k],  s1);
                s2 = fmaf(gk, xxv[j + k], s2);
                s3 = fmaf(gk, yyv[j + k], s3);
                s4 = fmaf(gk, xyv[j + k], s4);
            }
            vv[0][r0 + j][c] = s0;
            vv[1][r0 + j][c] = s1;
            vv[2][r0 + j][c] = s2;
            vv[3][r0 + j][c] = s3;
            vv[4][r0 + j][c] = s4;
        }
    }
    __syncthreads();

    // ---- Phase H: horizontal 11-tap conv + SSIM. Thread -> (row, 4-col group).
    // Output col j (image 64bx+j) taps vv[r][j+1 .. j+11]; quad j0 needs
    // vv[j0+1 .. j0+14] subset of aligned [j0 .. j0+16) -> 4x ds_read_b128 per q.
    const int r  = tid >> 4;            // 0..15
    const int j0 = (tid & 15) << 2;     // 0,4,...,60

    float acc[5][4];
    #pragma unroll
    for (int q = 0; q < 5; ++q) {
        const float4* vp = (const float4*)(&vv[q][r][j0]);
        const float4 A = vp[0], B = vp[1], C = vp[2], D = vp[3];
        const float win[16] = {A.x, A.y, A.z, A.w, B.x, B.y, B.z, B.w,
                               C.x, C.y, C.z, C.w, D.x, D.y, D.z, D.w};
        #pragma unroll
        for (int t = 0; t < 4; ++t) {
            float s = 0.f;
            #pragma unroll
            for (int k = 0; k < 11; ++k) s = fmaf(g[k], win[t + 1 + k], s);
            acc[q][t] = s;
        }
    }

    const float C1 = 1e-4f;   // 0.01^2
    const float C2 = 9e-4f;   // 0.03^2
    float local = 0.0f;
    #pragma unroll
    for (int t = 0; t < 4; ++t) {
        const float m1 = acc[0][t], m2 = acc[1][t];
        const float m1s = m1 * m1, m2s = m2 * m2, m12 = m1 * m2;
        const float v1  = acc[2][t] - m1s;
        const float v2  = acc[3][t] - m2s;
        const float v12 = acc[4][t] - m12;
        const float num = (2.0f * m12 + C1) * (2.0f * v12 + C2);
        const float den = (m1s + m2s + C1) * (v1 + v2 + C2);
        local += num / den;
    }

    // ---- Block reduction: wave shuffle -> LDS -> one store (or atomic) per block
    #pragma unroll
    for (int off = 32; off > 0; off >>= 1)
        local += __shfl_down(local, off, 64);
    if ((tid & 63) == 0) wsum[tid >> 6] = local;
    __syncthreads();
    if (tid == 0) {
        const double blk = (double)wsum[0] + (double)wsum[1]
                         + (double)wsum[2] + (double)wsum[3];
        if (use_atomic) {
            atomicAdd(part, blk);
        } else {
            const int bflat = blockIdx.x
                            + gridDim.x * (blockIdx.y + gridDim.y * blockIdx.z);
            part[bflat] = blk;
        }
    }
}

__global__ void ssim_reduce(const double* __restrict__ part, float* __restrict__ out,
                            int n)
{
    __shared__ double s[256];
    double t = 0.0;
    for (int i = threadIdx.x; i < n; i += 256) t += part[i];
    s[threadIdx.x] = t;
    __syncthreads();
    for (int off = 128; off > 0; off >>= 1) {
        if (threadIdx.x < off) s[threadIdx.x] += s[threadIdx.x + off];
        __syncthreads();
    }
    if (threadIdx.x == 0)
        out[0] = (float)(s[0] / (double)((size_t)NC * IMG_H * IMG_W));
}

extern "C" void kernel_launch(void* const* d_in, const int* in_sizes, int n_in,
                              void* d_out, int out_size, void* d_ws, size_t ws_size,
                              hipStream_t stream)
{
    const float* x = (const float*)d_in[0];
    const float* y = (const float*)d_in[1];
    const float* w = (const float*)d_in[2];
    double* part = (double*)d_ws;

    const bool fits = ws_size >= (size_t)NBLK * sizeof(double);
    dim3 grid(IMG_W / TW, IMG_H / TH, NC);   // (8, 32, 48) = 12288 blocks

    if (fits) {
        // every block writes its own slot; no memset, no atomics
        ssim_fused<<<grid, 256, 0, stream>>>(x, y, w, part, 0);
        ssim_reduce<<<1, 256, 0, stream>>>(part, (float*)d_out, NBLK);
    } else {
        hipMemsetAsync(d_ws, 0, sizeof(double), stream);
        ssim_fused<<<grid, 256, 0, stream>>>(x, y, w, part, 1);
        ssim_reduce<<<1, 256, 0, stream>>>(part, (float*)d_out, 1);
    }
}